// Round 1
// baseline (285.248 us; speedup 1.0000x reference)
//
#include <hip/hip_runtime.h>

#define Hh 51
#define TT 512
#define MR 2            // batch rows per block (A-rows 0 and 4)
#define NBLK 256        // 512 / MR -> one block per CU, all 256 CUs
#define BT 512          // 8 waves: 0-3 layer-1 (+wave3: out-proj), 4-7 layer-2
#define SHR 80          // H row stride in fp16 elems (160B)
#define NIT 516         // 512 steps + 4 pipeline-drain iterations (multiple of 4)
#define LOG2E 1.4426950408889634f

typedef _Float16 half8 __attribute__((ext_vector_type(8)));
typedef __attribute__((ext_vector_type(4))) float f32x4;

__device__ __forceinline__ float fexp2(float x){ return __builtin_amdgcn_exp2f(x); }
__device__ __forceinline__ float frcp(float x){ return __builtin_amdgcn_rcpf(x); }
__device__ __forceinline__ float sigm(float x){ return frcp(1.f + fexp2(-LOG2E*x)); }
__device__ __forceinline__ float ftanh(float x){ return 1.f - 2.f*frcp(1.f + fexp2(2.f*LOG2E*x)); }
__device__ __forceinline__ unsigned short h16bits(_Float16 h){
    union { _Float16 h; unsigned short u; } c; c.h = h; return c.u;
}
// pack float -> fp16 hi/lo pair in one uint (hi in low 16, lo in high 16)
__device__ __forceinline__ unsigned packhl(float v){
    _Float16 hi = (_Float16)v;
    _Float16 lo = (_Float16)(v - (float)hi);
    return (unsigned)h16bits(hi) | ((unsigned)h16bits(lo) << 16);
}

#define MFMAH(a,b,c) __builtin_amdgcn_mfma_f32_16x16x32_f16(a,b,c,0,0,0)

__global__ __launch_bounds__(BT, 2) void lstm2_fold(
    const float* __restrict__ input,   // [512,512]
    const float* __restrict__ W_ih1,   // [204]
    const float* __restrict__ W_hh1,   // [204,51]
    const float* __restrict__ b_ih1,
    const float* __restrict__ b_hh1,
    const float* __restrict__ W_ih2,   // [204,51]
    const float* __restrict__ W_hh2,   // [204,51]
    const float* __restrict__ b_ih2,
    const float* __restrict__ b_hh2,
    const float* __restrict__ W_lin,   // [51]
    const float* __restrict__ b_lin,   // [1]
    float* __restrict__ out)           // [512,512]
{
    __shared__ unsigned xsp[(TT+1)*MR];  // packed fp16 hi/lo x[t][m]
    __shared__ float ob[TT*MR];          // out[t][m]
    // h state, A-frag layout [m][k] fp16, 4-deep parity ring.
    // h1(t) lives in H1[t&3]; h2(t) lives in H2[t&3] (written at iter t+2).
    // Live A-rows: 0, 4. K-slots per row: 0..50 = h, 51 = 1.0, 52/53 = x_hi/x_lo, 54 = 1.0.
    __shared__ __align__(16) _Float16 H1[4][16*SHR];
    __shared__ __align__(16) _Float16 H2[4][16*SHR];

    const int tid  = threadIdx.x;
    const int wv   = tid >> 6;
    const int lane = tid & 63;
    const int quad = lane >> 4;
    const int n16  = lane & 15;
    const int row0 = blockIdx.x * MR;
    const bool g1  = (wv < 4);
    const bool w3  = (wv == 3);
    const int  w   = g1 ? wv : (wv - 4);       // wave index within group
    const int  l   = 13 * w + n16;             // hidden unit owned by this lane-column
    const bool valid = (n16 <= 12) && (l < Hh);
    const bool liveA = ((n16 & 11) == 0);      // n16 in {0,4}: the two live A-rows
    const bool updL  = (quad < MR) && valid;   // lanes doing the gate/state update
    const bool xw    = (wv == 0) && (n16 == 0) && (quad < MR);  // x-forward lanes
    const int  fo    = n16 * SHR + quad * 8;   // A-frag element offset (loop-invariant)
    const int  ho    = (quad * 4) * SHR + l;   // h store offset (rows 0 / 4)

    // ---- stage input rows as packed fp16 hi/lo (coalesced in t)
#pragma unroll
    for (int i = 0; i < MR; ++i) {
        int idx = i * BT + tid; int m = idx >> 9, t = idx & 511;
        xsp[t * MR + m] = packhl(input[(row0 + m) * TT + t]);
    }
    if (tid < MR) xsp[TT * MR + tid] = 0u;     // tail (x(512) read at n=511)
    // ---- zero h buffers (all 4 parities; all rows)
    for (int i = tid; i < 4 * 16 * SHR / 2; i += BT) {
        ((int*)H1)[i] = 0; ((int*)H2)[i] = 0;
    }

    // ---- persistent weight B-fragments (fp16), gate-interleaved permutation:
    // tile gt (gate i,f,g,o), col c=n16  <->  weight row gt*51 + (13w+c)
    // K-columns 51..54 carry the affine epilogue: [bias_hi, wih, wih, bias_lo]
    half8 z8 = {0,0,0,0,0,0,0,0};
    half8 B1[4][2];                // W_hh1 (+bias1/wih slots)  (group 1)
    half8 B2[4][2], B3[4][2];      // W_ih2 (+bias2), W_hh2 (group 2)
    half8 Bout[2];                 // W_lin (+blin) column (wave 3)
    const f32x4 zc = (f32x4){0.f,0.f,0.f,0.f};   // persistent zero accumulator seed
#pragma unroll
    for (int gt = 0; gt < 4; ++gt) {
        int jrow = gt * Hh + l;
        float bias = 0.f, wih = 0.f;
        if (valid) {
            bias = g1 ? (b_ih1[jrow] + b_hh1[jrow]) : (b_ih2[jrow] + b_hh2[jrow]);
            wih  = g1 ? W_ih1[jrow] : 0.f;
        }
        _Float16 bhi = (_Float16)bias;
        _Float16 blo = (_Float16)(bias - (float)bhi);
        _Float16 wih_h = (_Float16)wih;
#pragma unroll
        for (int kt = 0; kt < 2; ++kt) {
            B1[gt][kt] = z8; B2[gt][kt] = z8; B3[gt][kt] = z8;
#pragma unroll
            for (int jj = 0; jj < 8; ++jj) {
                int k = kt * 32 + quad * 8 + jj;
                if (valid) {
                    if (g1) {
                        if (k < Hh)       B1[gt][kt][jj] = (_Float16)W_hh1[jrow * Hh + k];
                        else if (k == 51) B1[gt][kt][jj] = bhi;
                        else if (k == 52 || k == 53) B1[gt][kt][jj] = wih_h;
                        else if (k == 54) B1[gt][kt][jj] = blo;
                    } else {
                        if (k < Hh) {
                            B2[gt][kt][jj] = (_Float16)W_ih2[jrow * Hh + k];
                            B3[gt][kt][jj] = (_Float16)W_hh2[jrow * Hh + k];
                        } else if (k == 51) B2[gt][kt][jj] = bhi;
                        else if (k == 54)   B2[gt][kt][jj] = blo;
                    }
                }
            }
        }
    }
    {
        float blf = b_lin[0];
        _Float16 blhi = (_Float16)blf;
        _Float16 bllo = (_Float16)(blf - (float)blhi);
#pragma unroll
        for (int kt = 0; kt < 2; ++kt) {
            Bout[kt] = z8;
#pragma unroll
            for (int jj = 0; jj < 8; ++jj) {
                int k = kt * 32 + quad * 8 + jj;
                if (w3 && n16 == 0) {
                    if (k < Hh)       Bout[kt][jj] = (_Float16)W_lin[k];
                    else if (k == 51) Bout[kt][jj] = blhi;
                    else if (k == 54) Bout[kt][jj] = bllo;
                }
            }
        }
    }
    float cst = 0.f;   // cell state: quad0 lanes -> batch row 0, quad1 -> row 1 (unit l)

    // A-fragment registers persist; masked-out lanes keep zero.
    half8 f1a = z8, f1b = z8;          // h1 frags (group 1, critical)
    half8 f2a = z8, f2b = z8;          // h2 frags (group 2, critical)
    half8 pf1a = z8, pf1b = z8;        // group 2: prefetched h1(n-1) for next iter's aB
    half8 of2a = z8, of2b = z8;        // wave 3: prefetched h2(n-4) for out-proj

    __syncthreads();
    // ---- constant K-slots (after zeroing): rows 0,4; all 4 parities; x(0) into slot 3
    if (tid < MR) {
        int r = tid * 4 * SHR;
#pragma unroll
        for (int p = 0; p < 4; ++p) {
            H1[p][r + 51] = (_Float16)1.0f;  H1[p][r + 54] = (_Float16)1.0f;
            H2[p][r + 51] = (_Float16)1.0f;  H2[p][r + 54] = (_Float16)1.0f;
        }
        *(unsigned*)&H1[3][r + 52] = xsp[tid];   // x(0) hi/lo (iter 0 reads slot 3)
    }
    __syncthreads();

    // Slot algebra at iteration n (P = n&3):
    //   G1 reads  h1(n-1) from slot (P+3)&3, writes h1(n) to slot P (with x(n+1)).
    //   G2 reads  h2(n-3) from slot (P+1)&3, writes h2(n-2) to slot (P+2)&3.
    //   G2 aB uses pf1 = h1(n-2) (read last iter); prefetches h1(n-1) from (P+3)&3.
    //   W3 out(n-4) uses of2 = h2(n-4) (read last iter); prefetches h2(n-3) from (P+1)&3.
    // All 4 slots distinct each iteration -> no read/write races.
    auto stepfn = [&](int n, int P) {
        const int Sr1 = (P + 3) & 3;
        const int Sw1 = P;
        const int Sr2 = (P + 1) & 3;
        const int Sw2 = (P + 2) & 3;
        if (g1) {
            if (n < TT) {
                // ---- layer-1, time n: z1 = Whh1·[h1(n-1),1,x(n)]  (epilogue in K-slack)
                unsigned xn = xw ? xsp[(n + 1) * MR + quad] : 0u;   // x(n+1) forward
                if (liveA) {
                    f1a = *(const half8*)&H1[Sr1][fo];
                    f1b = *(const half8*)&H1[Sr1][fo + 32];
                }
                // wave3 out-proj: runs entirely inside the f1-read shadow (of2 is
                // last iter's prefetch = h2(n-4); prefetch of h2(n-3) reissued after).
                if (w3) {
                    if (n >= 4) {
                        f32x4 ao = MFMAH(of2a, Bout[0], zc);
                        ao       = MFMAH(of2b, Bout[1], ao);
                        if (n16 == 0 && quad < MR) ob[(n - 4) * MR + quad] = ao[0];
                    }
                    if (liveA) {
                        of2a = *(const half8*)&H2[Sr2][fo];
                        of2b = *(const half8*)&H2[Sr2][fo + 32];
                    }
                }
                // split gate chains: two independent depth-1 MFMAs + scalar add
                float vg[4];
#pragma unroll
                for (int gt = 0; gt < 4; ++gt) {
                    f32x4 m1 = MFMAH(f1a, B1[gt][0], zc);
                    f32x4 m2 = MFMAH(f1b, B1[gt][1], zc);
                    vg[gt] = m1[0] + m2[0];
                }
                if (updL) {
                    float ii = sigm(vg[0]), ff = sigm(vg[1]);
                    float gg = ftanh(vg[2]), oo = sigm(vg[3]);
                    cst = fmaf(ff, cst, ii * gg);
                    float h = oo * ftanh(cst);
                    H1[Sw1][ho] = (_Float16)h;
                }
                if (xw) *(unsigned*)&H1[Sw1][(quad * 4) * SHR + 52] = xn;
            } else if (w3) {
                // drain iterations: out-proj only
                f32x4 ao = MFMAH(of2a, Bout[0], zc);
                ao       = MFMAH(of2b, Bout[1], ao);
                if (n16 == 0 && quad < MR) ob[(n - 4) * MR + quad] = ao[0];
                if (liveA) {
                    of2a = *(const half8*)&H2[Sr2][fo];
                    of2b = *(const half8*)&H2[Sr2][fo + 32];
                }
            }
        } else {
            // ---- layer-2, time n-2: z2 = Whh2·h2(n-3) + Wih2·[h1(n-2),1]
            // critical read: h2(n-3)
            if (liveA) {
                f2a = *(const half8*)&H2[Sr2][fo];
                f2b = *(const half8*)&H2[Sr2][fo + 32];
            }
            // off-critical: aB = Wih2·h1(n-2) from pf1 (registers, issues in D-shadow)
            f32x4 aB[4];
#pragma unroll
            for (int gt = 0; gt < 4; ++gt) {
                f32x4 a = MFMAH(pf1a, B2[gt][0], zc);
                aB[gt]  = MFMAH(pf1b, B2[gt][1], a);
            }
            // prefetch h1(n-1) for next iteration (data valid since barrier(n-1);
            // issues after aB consumed old pf1, returns inside this iter)
            if (liveA) {
                pf1a = *(const half8*)&H1[Sr1][fo];
                pf1b = *(const half8*)&H1[Sr1][fo + 32];
            }
            if (n >= 2 && n < TT + 2) {
                float vg[4];
#pragma unroll
                for (int gt = 0; gt < 4; ++gt) {
                    f32x4 m1 = MFMAH(f2a, B3[gt][0], zc);
                    f32x4 m2 = MFMAH(f2b, B3[gt][1], zc);
                    vg[gt] = m1[0] + m2[0] + aB[gt][0];
                }
                if (updL) {
                    float ii = sigm(vg[0]), ff = sigm(vg[1]);
                    float gg = ftanh(vg[2]), oo = sigm(vg[3]);
                    cst = fmaf(ff, cst, ii * gg);
                    float h = oo * ftanh(cst);
                    H2[Sw2][ho] = (_Float16)h;
                }
            }
        }
        __syncthreads();   // publishes h1(n), x(n+1), h2(n-2) for iteration n+1
    };

    // unroll x4: ring-slot literals fold all LDS addressing to base+constant
    for (int k4 = 0; k4 < NIT / 4; ++k4) {
        int b = 4 * k4;
        stepfn(b + 0, 0);
        stepfn(b + 1, 1);
        stepfn(b + 2, 2);
        stepfn(b + 3, 3);
    }

    // ---- flush outputs (coalesced in t)
#pragma unroll
    for (int i = 0; i < MR; ++i) {
        int idx = i * BT + tid; int m = idx >> 9, t = idx & 511;
        out[(row0 + m) * TT + t] = ob[t * MR + m];
    }
}

extern "C" void kernel_launch(void* const* d_in, const int* in_sizes, int n_in,
                              void* d_out, int out_size, void* d_ws, size_t ws_size,
                              hipStream_t stream) {
    const float* input = (const float*)d_in[0];
    const float* W_ih1 = (const float*)d_in[1];
    const float* W_hh1 = (const float*)d_in[2];
    const float* b_ih1 = (const float*)d_in[3];
    const float* b_hh1 = (const float*)d_in[4];
    const float* W_ih2 = (const float*)d_in[5];
    const float* W_hh2 = (const float*)d_in[6];
    const float* b_ih2 = (const float*)d_in[7];
    const float* b_hh2 = (const float*)d_in[8];
    const float* W_lin = (const float*)d_in[9];
    const float* b_lin = (const float*)d_in[10];
    float* out = (float*)d_out;

    hipLaunchKernelGGL(lstm2_fold, dim3(NBLK), dim3(BT), 0, stream,
                       input, W_ih1, W_hh1, b_ih1, b_hh1,
                       W_ih2, W_hh2, b_ih2, b_hh2, W_lin, b_lin, out);
}

// Round 2
// 280.759 us; speedup vs baseline: 1.0160x; 1.0160x over previous
//
#include <hip/hip_runtime.h>

#define Hh 51
#define TT 512
#define MR 2            // batch rows per block (A-rows 0 and 4)
#define NBLK 256        // 512 / MR -> one block per CU, all 256 CUs
#define BT 512          // 8 waves: 0-3 layer-1 (+wave3: out-proj), 4-7 layer-2
#define SHR 80          // H row stride in fp16 elems (160B)
#define NIT 514         // 512 steps + 2 pipeline-drain iterations (even)
#define LOG2E 1.4426950408889634f

typedef _Float16 half8 __attribute__((ext_vector_type(8)));
typedef __attribute__((ext_vector_type(4))) float f32x4;

__device__ __forceinline__ float fexp2(float x){ return __builtin_amdgcn_exp2f(x); }
__device__ __forceinline__ float frcp(float x){ return __builtin_amdgcn_rcpf(x); }
__device__ __forceinline__ unsigned short h16bits(_Float16 h){
    union { _Float16 h; unsigned short u; } c; c.h = h; return c.u;
}
// pack float -> fp16 hi/lo pair in one uint (hi in low 16, lo in high 16)
__device__ __forceinline__ unsigned packhl(float v){
    _Float16 hi = (_Float16)v;
    _Float16 lo = (_Float16)(v - (float)hi);
    return (unsigned)h16bits(hi) | ((unsigned)h16bits(lo) << 16);
}

// LSTM state update with pre-scaled gate inputs:
//   vg0 = -LOG2E*zi, vg1 = -LOG2E*zf, vg2 = 2*LOG2E*zg, vg3 = -LOG2E*zo
// (scales folded into the weight fragments). Common-denominator form:
// 7 transcendentals (5 exp2 + 2 rcp) instead of 10.
__device__ __forceinline__ float lstm_update(float vg0, float vg1, float vg2,
                                             float vg3, float& cst){
    float e_i = fexp2(vg0);          // e^{-zi}
    float e_f = fexp2(vg1);          // e^{-zf}
    float e_g = fexp2(vg2);          // e^{+2 zg}
    float e_o = fexp2(vg3);          // e^{-zo}
    float a_i = e_i + 1.f, a_f = e_f + 1.f;
    float gp  = e_g + 1.f, gm = e_g - 1.f, a_o = e_o + 1.f;
    // c' = c/(1+e_f) + (e_g-1)/((1+e_i)(e_g+1))
    float u  = a_i * gp;
    float N  = fmaf(cst, u, gm * a_f);
    float rD = frcp(a_f * u);
    cst = N * rD;
    // h = (e_c-1)/((e_c+1)(1+e_o)), e_c = e^{2 c'} (clamped: tanh saturated)
    float zc2 = fminf(2.f * LOG2E * cst, 60.f);
    float e_c = fexp2(zc2);
    float r2  = frcp((e_c + 1.f) * a_o);
    return (e_c - 1.f) * r2;
}

#define MFMAH(a,b,c) __builtin_amdgcn_mfma_f32_16x16x32_f16(a,b,c,0,0,0)

__global__ __launch_bounds__(BT, 2) void lstm2_fold(
    const float* __restrict__ input,   // [512,512]
    const float* __restrict__ W_ih1,   // [204]
    const float* __restrict__ W_hh1,   // [204,51]
    const float* __restrict__ b_ih1,
    const float* __restrict__ b_hh1,
    const float* __restrict__ W_ih2,   // [204,51]
    const float* __restrict__ W_hh2,   // [204,51]
    const float* __restrict__ b_ih2,
    const float* __restrict__ b_hh2,
    const float* __restrict__ W_lin,   // [51]
    const float* __restrict__ b_lin,   // [1]
    float* __restrict__ out)           // [512,512]
{
    __shared__ unsigned xsp[(TT+1)*MR];  // packed fp16 hi/lo x[t][m]
    __shared__ float ob[TT*MR];          // out[t][m]
    // h state, A-frag layout [m][k] fp16, double-buffered by parity.
    // Live A-rows: 0, 4. K-slots per row: 0..50 = h, 51 = 1.0, 52/53 = x_hi/x_lo, 54 = 1.0.
    __shared__ __align__(16) _Float16 H1[2][16*SHR];
    __shared__ __align__(16) _Float16 H2[2][16*SHR];

    const int tid  = threadIdx.x;
    const int wv   = tid >> 6;
    const int lane = tid & 63;
    const int quad = lane >> 4;
    const int n16  = lane & 15;
    const int row0 = blockIdx.x * MR;
    const bool g1  = (wv < 4);
    const bool w3  = (wv == 3);
    const int  w   = g1 ? wv : (wv - 4);       // wave index within group
    const int  l   = 13 * w + n16;             // hidden unit owned by this lane-column
    const bool valid = (n16 <= 12) && (l < Hh);
    const bool liveA = ((n16 & 11) == 0);      // n16 in {0,4}: the two live A-rows
    const bool updL  = (quad < MR) && valid;   // lanes doing the gate/state update
    const bool xw    = (wv == 0) && (n16 == 0) && (quad < MR);  // x-forward lanes
    const int  fo    = n16 * SHR + quad * 8;   // A-frag element offset (loop-invariant)
    const int  ho    = (quad * 4) * SHR + l;   // h store offset (rows 0 / 4)

    // ---- stage input rows as packed fp16 hi/lo (coalesced in t)
#pragma unroll
    for (int i = 0; i < MR; ++i) {
        int idx = i * BT + tid; int m = idx >> 9, t = idx & 511;
        xsp[t * MR + m] = packhl(input[(row0 + m) * TT + t]);
    }
    if (tid < MR) xsp[TT * MR + tid] = 0u;     // tail (x(512) read at n=511)
    // ---- zero h buffers (both parities; all rows)
    for (int i = tid; i < 2 * 16 * SHR / 2; i += BT) {
        ((int*)H1)[i] = 0; ((int*)H2)[i] = 0;
    }

    // ---- persistent weight B-fragments (fp16), gate-interleaved permutation:
    // tile gt (gate i,f,g,o), col c=n16  <->  weight row gt*51 + (13w+c)
    // Gate scale factors folded into weights/biases BEFORE fp16 rounding:
    //   i,f,o: -LOG2E  (sigmoid via e = 2^{-LOG2E z});  g: +2*LOG2E (tanh form).
    // K-columns 51..54 carry the affine epilogue: [bias_hi, wih, wih, bias_lo]
    half8 z8 = {0,0,0,0,0,0,0,0};
    half8 B1[4][2];                // W_hh1 (+bias1/wih slots)  (group 1)
    half8 B2[4][2], B3[4][2];      // W_ih2 (+bias2), W_hh2 (group 2)
    half8 Bout[2];                 // W_lin (+blin) column (wave 3)
    const f32x4 zc = (f32x4){0.f,0.f,0.f,0.f};   // persistent zero accumulator seed
#pragma unroll
    for (int gt = 0; gt < 4; ++gt) {
        const float gs = (gt == 2) ? (2.f * LOG2E) : (-LOG2E);   // gate scale
        int jrow = gt * Hh + l;
        float bias = 0.f, wih = 0.f;
        if (valid) {
            bias = gs * (g1 ? (b_ih1[jrow] + b_hh1[jrow]) : (b_ih2[jrow] + b_hh2[jrow]));
            wih  = g1 ? (gs * W_ih1[jrow]) : 0.f;
        }
        _Float16 bhi = (_Float16)bias;
        _Float16 blo = (_Float16)(bias - (float)bhi);
        _Float16 wih_h = (_Float16)wih;
#pragma unroll
        for (int kt = 0; kt < 2; ++kt) {
            B1[gt][kt] = z8; B2[gt][kt] = z8; B3[gt][kt] = z8;
#pragma unroll
            for (int jj = 0; jj < 8; ++jj) {
                int k = kt * 32 + quad * 8 + jj;
                if (valid) {
                    if (g1) {
                        if (k < Hh)       B1[gt][kt][jj] = (_Float16)(gs * W_hh1[jrow * Hh + k]);
                        else if (k == 51) B1[gt][kt][jj] = bhi;
                        else if (k == 52 || k == 53) B1[gt][kt][jj] = wih_h;
                        else if (k == 54) B1[gt][kt][jj] = blo;
                    } else {
                        if (k < Hh) {
                            B2[gt][kt][jj] = (_Float16)(gs * W_ih2[jrow * Hh + k]);
                            B3[gt][kt][jj] = (_Float16)(gs * W_hh2[jrow * Hh + k]);
                        } else if (k == 51) B2[gt][kt][jj] = bhi;
                        else if (k == 54)   B2[gt][kt][jj] = blo;
                    }
                }
            }
        }
    }
    {
        float blf = b_lin[0];
        _Float16 blhi = (_Float16)blf;
        _Float16 bllo = (_Float16)(blf - (float)blhi);
#pragma unroll
        for (int kt = 0; kt < 2; ++kt) {
            Bout[kt] = z8;
#pragma unroll
            for (int jj = 0; jj < 8; ++jj) {
                int k = kt * 32 + quad * 8 + jj;
                if (w3 && n16 == 0) {
                    if (k < Hh)       Bout[kt][jj] = (_Float16)W_lin[k];
                    else if (k == 51) Bout[kt][jj] = blhi;
                    else if (k == 54) Bout[kt][jj] = bllo;
                }
            }
        }
    }
    float cst = 0.f;   // cell state: quad0 lanes -> batch row 0, quad1 -> row 1 (unit l)

    // A-fragment registers persist; masked-out lanes keep zero.
    half8 f1a = z8, f1b = z8;      // h1 frags
    half8 f2a = z8, f2b = z8;      // h2 frags (g2 + wave3-out)

    __syncthreads();
    // ---- constant K-slots (after zeroing): rows 0,4; both parities; x(0) into parity 1
    if (tid < MR) {
        int r = tid * 4 * SHR;
#pragma unroll
        for (int p = 0; p < 2; ++p) {
            H1[p][r + 51] = (_Float16)1.0f;  H1[p][r + 54] = (_Float16)1.0f;
            H2[p][r + 51] = (_Float16)1.0f;  H2[p][r + 54] = (_Float16)1.0f;
        }
        *(unsigned*)&H1[1][r + 52] = xsp[tid];   // x(0) hi/lo for step 0 (reads parity 1)
    }
    __syncthreads();

    // one pipeline step; pA/pB are compile-time literals at call sites.
    // ALL LDS reads issue at step start (consumed mid-step) so the compiler's
    // pre-barrier lgkmcnt(0) drain never exposes read latency (round-1 lesson).
    auto stepfn = [&](int n, int pA, int pB) {
        if (g1) {
            if (w3 && n >= 2) {                // out-proj frags: h2(n-2)
                if (liveA) {
                    f2a = *(const half8*)&H2[pB][fo];
                    f2b = *(const half8*)&H2[pB][fo + 32];
                }
            }
            if (n < TT) {
                // ---- layer-1, time n: z1 = Whh1·[h1(n-1),1,x(n)]  (epilogue in K-slack)
                unsigned xn = xw ? xsp[(n + 1) * MR + quad] : 0u;   // x(n+1) forward
                if (liveA) {
                    f1a = *(const half8*)&H1[pA][fo];
                    f1b = *(const half8*)&H1[pA][fo + 32];
                }
                f32x4 ac[4];
#pragma unroll
                for (int gt = 0; gt < 4; ++gt) {
                    f32x4 a = MFMAH(f1a, B1[gt][0], zc);
                    a       = MFMAH(f1b, B1[gt][1], a);
                    ac[gt] = a;
                }
                if (updL) {
                    float h = lstm_update(ac[0][0], ac[1][0], ac[2][0], ac[3][0], cst);
                    H1[pB][ho] = (_Float16)h;
                }
                if (xw) *(unsigned*)&H1[pB][(quad * 4) * SHR + 52] = xn;
            }
            if (w3 && n >= 2) {
                // out(n-2) = W_lin·h2(n-2) + blin   (bias in K-slack)
                f32x4 ao = MFMAH(f2a, Bout[0], zc);
                ao       = MFMAH(f2b, Bout[1], ao);
                if (n16 == 0 && quad < MR) ob[(n - 2) * MR + quad] = ao[0];
            }
        } else if (n >= 1 && n <= TT) {
            // ---- layer-2, time n-1: z2 = Wih2·[h1(n-1),1] + Whh2·h2(n-2)
            if (liveA) {
                f1a = *(const half8*)&H1[pA][fo];
                f1b = *(const half8*)&H1[pA][fo + 32];
                f2a = *(const half8*)&H2[pB][fo];
                f2b = *(const half8*)&H2[pB][fo + 32];
            }
            // two independent 2-chains (h2-part, h1-part) + one add:
            // halves the MFMA dependency depth vs a single 4-chain.
            float vg[4];
#pragma unroll
            for (int gt = 0; gt < 4; ++gt) {
                f32x4 m2 = MFMAH(f2a, B3[gt][0], zc);
                m2       = MFMAH(f2b, B3[gt][1], m2);
                f32x4 m1 = MFMAH(f1a, B2[gt][0], zc);
                m1       = MFMAH(f1b, B2[gt][1], m1);
                vg[gt] = m2[0] + m1[0];
            }
            if (updL) {
                float h = lstm_update(vg[0], vg[1], vg[2], vg[3], cst);
                H2[pA][ho] = (_Float16)h;
            }
        }
        __syncthreads();   // publishes h1(n), x(n+1), h2(n-1) for iteration n+1
    };

    // unroll x2: parity literals fold all LDS addressing to base+constant
    for (int k2 = 0; k2 < NIT / 2; ++k2) {
        stepfn(2 * k2,     1, 0);
        stepfn(2 * k2 + 1, 0, 1);
    }

    // ---- flush outputs (coalesced in t)
#pragma unroll
    for (int i = 0; i < MR; ++i) {
        int idx = i * BT + tid; int m = idx >> 9, t = idx & 511;
        out[(row0 + m) * TT + t] = ob[t * MR + m];
    }
}

extern "C" void kernel_launch(void* const* d_in, const int* in_sizes, int n_in,
                              void* d_out, int out_size, void* d_ws, size_t ws_size,
                              hipStream_t stream) {
    const float* input = (const float*)d_in[0];
    const float* W_ih1 = (const float*)d_in[1];
    const float* W_hh1 = (const float*)d_in[2];
    const float* b_ih1 = (const float*)d_in[3];
    const float* b_hh1 = (const float*)d_in[4];
    const float* W_ih2 = (const float*)d_in[5];
    const float* W_hh2 = (const float*)d_in[6];
    const float* b_ih2 = (const float*)d_in[7];
    const float* b_hh2 = (const float*)d_in[8];
    const float* W_lin = (const float*)d_in[9];
    const float* b_lin = (const float*)d_in[10];
    float* out = (float*)d_out;

    hipLaunchKernelGGL(lstm2_fold, dim3(NBLK), dim3(BT), 0, stream,
                       input, W_ih1, W_hh1, b_ih1, b_hh1,
                       W_ih2, W_hh2, b_ih2, b_hh2, W_lin, b_lin, out);
}